// Round 1
// baseline (458.180 us; speedup 1.0000x reference)
//
#include <hip/hip_runtime.h>

// ---------------- ws (meta) layout, units of 4 bytes ----------------
#define META_SI    0      // f32[256] scale per input channel
#define META_SO    256    // f32[256] scale per filter
#define META_GIN   512    // i32[256] group per input channel
#define META_GOUT  768    // i32[256] group per filter
#define META_CLIST 1024   // i32[256] input channels, group-major stable
#define META_FLIST 1280   // i32[256] filters, group-major stable (= perm)
#define META_DEST  1536   // i32[256] dest[f] = output channel for filter f
#define META_CBASE 1792   // i32[8]
#define META_FBASE 1808   // i32[8]
#define META_WOFF  1824   // i32[9] packed-weight offsets (floats), [8]=total
#define META_CCNT  1840   // i32[8]
#define META_FCNT  1856   // i32[8]
#define META_WPACK 2048   // f32[...] packed scaled weights

__global__ __launch_bounds__(256) void flgc_setup(const float* __restrict__ S,
                                                  const float* __restrict__ T,
                                                  int* __restrict__ meta) {
    __shared__ float si[256], so[256];
    __shared__ int gin[256], gout[256];
    __shared__ int cnt_in[8], cnt_out[8], cb[8], fb[8];
    __shared__ int perm[256], destl[256];
    const int c = threadIdx.x;  // 0..255

    {   // softmax max-value + argmax (first occurrence) for S row c
        float m = S[c * 8]; int am = 0;
        for (int k = 1; k < 8; ++k) { float v = S[c * 8 + k]; if (v > m) { m = v; am = k; } }
        float s = 0.f;
        for (int k = 0; k < 8; ++k) s += expf(S[c * 8 + k] - m);
        si[c] = 1.0f / s; gin[c] = am;
    }
    {   // same for T row c
        float m = T[c * 8]; int am = 0;
        for (int k = 1; k < 8; ++k) { float v = T[c * 8 + k]; if (v > m) { m = v; am = k; } }
        float s = 0.f;
        for (int k = 0; k < 8; ++k) s += expf(T[c * 8 + k] - m);
        so[c] = 1.0f / s; gout[c] = am;
    }
    __syncthreads();
    const int g = gin[c], go = gout[c];
    int r1 = 0, r2 = 0;  // stable rank within group
    for (int i = 0; i < c; ++i) { r1 += (gin[i] == g); r2 += (gout[i] == go); }
    if (c < 8) {
        int n1 = 0, n2 = 0;
        for (int i = 0; i < 256; ++i) { n1 += (gin[i] == c); n2 += (gout[i] == c); }
        cnt_in[c] = n1; cnt_out[c] = n2;
    }
    __syncthreads();
    if (c == 0) {
        int a = 0, b = 0;
        for (int k = 0; k < 8; ++k) { cb[k] = a; a += cnt_in[k]; fb[k] = b; b += cnt_out[k]; }
    }
    __syncthreads();
    meta[META_CLIST + cb[g] + r1] = c;   // group-major input channel list
    perm[fb[go] + r2] = c;               // group-major filter list == argsort(t stable)
    __syncthreads();
    const int ppc = perm[perm[c]];       // pp[j] with j = c
    destl[ppc] = c;                      // dest[pp[j]] = j  (pp is a permutation)
    __syncthreads();
    ((float*)meta)[META_SI + c] = si[c];
    ((float*)meta)[META_SO + c] = so[c];
    meta[META_GIN + c]  = gin[c];
    meta[META_GOUT + c] = gout[c];
    meta[META_FLIST + c] = perm[c];
    meta[META_DEST + c]  = destl[c];
    if (c < 8) {
        meta[META_CBASE + c] = cb[c];
        meta[META_FBASE + c] = fb[c];
        meta[META_CCNT + c]  = cnt_in[c];
        meta[META_FCNT + c]  = cnt_out[c];
    }
    if (c == 0) {
        int a = 0;
        for (int k = 0; k < 8; ++k) { meta[META_WOFF + k] = a; a += cnt_out[k] * cnt_in[k] * 9; }
        meta[META_WOFF + 8] = a;
    }
}

// wpack[woff[g] + (ol*ccnt + cl)*9 + tap] = conv[f, ch, kh, kw] * si[ch] * so[f]
__global__ void flgc_pack(const float* __restrict__ conv, const int* __restrict__ meta,
                          float* __restrict__ wpack) {
    const float* si = (const float*)meta + META_SI;
    const float* so = (const float*)meta + META_SO;
    const int total = meta[META_WOFF + 8];
    for (int idx = blockIdx.x * blockDim.x + threadIdx.x; idx < total;
         idx += gridDim.x * blockDim.x) {
        int gg = 0;
        while (gg < 7 && idx >= meta[META_WOFF + gg + 1]) ++gg;
        const int local = idx - meta[META_WOFF + gg];
        const int cc = meta[META_CCNT + gg];
        const int ol = local / (cc * 9);
        const int rem = local - ol * cc * 9;
        const int cl = rem / 9;
        const int tap = rem - cl * 9;
        const int f  = meta[META_FLIST + meta[META_FBASE + gg] + ol];
        const int ch = meta[META_CLIST + meta[META_CBASE + gg] + cl];
        wpack[idx] = conv[(f * 256 + ch) * 9 + tap] * si[ch] * so[f];
    }
}

// Direct grouped conv. Block = (group g, batch b, 4-row stripe).
// 256 threads = 64 cols x 4 oc-quarters. Each thread: 4 rows x up to 16 out-chans.
__global__ __launch_bounds__(256, 2) void flgc_conv(const float* __restrict__ x,
                                                    const int* __restrict__ meta,
                                                    const float* __restrict__ wpack,
                                                    float* __restrict__ out) {
    __shared__ float xlds[8][6][64];   // [c-chunk][row h0-1..h0+4][col -1..62]
    __shared__ float wlds[64][8][12];  // [oc][c-chunk][tap, padded to 12]
    const int g   = blockIdx.z;
    const int b   = blockIdx.y;
    const int h0  = blockIdx.x * 4;
    const int tid = threadIdx.x;
    const int col = tid & 63;
    const int ocq = tid >> 6;          // wave id: all 64 lanes share ocq
    const int ccnt = meta[META_CCNT + g];
    const int fcnt = meta[META_FCNT + g];
    const int cbas = meta[META_CBASE + g];
    const int fbas = meta[META_FBASE + g];
    const int woff = meta[META_WOFF + g];
    const int colr = col < 56 ? col : 55;   // clamp for in-bounds LDS reads

    for (int oc0 = 0; oc0 < fcnt; oc0 += 64) {
        const int onum = min(64, fcnt - oc0);
        const int kmax = (onum - ocq + 3) >> 2;   // #k with ocq+4k < onum (wave-uniform)
        float acc[4][16];
#pragma unroll
        for (int r = 0; r < 4; ++r)
#pragma unroll
            for (int k = 0; k < 16; ++k) acc[r][k] = 0.f;

        for (int c0 = 0; c0 < ccnt; c0 += 8) {
            const int cch = min(8, ccnt - c0);
            __syncthreads();
            // stage x halo tile (zero-padded borders), coalesced: i%64 = col
            for (int i = tid; i < cch * 384; i += 256) {
                const int cl  = i / 384;
                const int rem = i - cl * 384;
                const int rr  = rem >> 6;
                const int cc  = rem & 63;
                const int chn = meta[META_CLIST + cbas + c0 + cl];
                const int row = h0 - 1 + rr;
                const int colx = cc - 1;
                float v = 0.f;
                if ((unsigned)row < 56u && (unsigned)colx < 56u)
                    v = x[((b * 256 + chn) * 56 + row) * 56 + colx];
                xlds[cl][rr][cc] = v;
            }
            // stage weight chunk
            const int wn = onum * cch * 9;
            for (int i = tid; i < wn; i += 256) {
                const int ol  = i / (cch * 9);
                const int rem = i - ol * cch * 9;
                const int cl  = rem / 9;
                const int tap = rem - cl * 9;
                wlds[ol][cl][tap] = wpack[woff + ((oc0 + ol) * ccnt + (c0 + cl)) * 9 + tap];
            }
            __syncthreads();
            for (int cl = 0; cl < cch; ++cl) {
                float xv[6][3];
#pragma unroll
                for (int rr = 0; rr < 6; ++rr)
#pragma unroll
                    for (int d = 0; d < 3; ++d)
                        xv[rr][d] = xlds[cl][rr][colr + d];
#pragma unroll
                for (int k = 0; k < 16; ++k) {
                    if (k < kmax) {   // wave-uniform guard; acc stays statically indexed
                        const int ol = ocq + 4 * k;
                        const float* wp = &wlds[ol][cl][0];
                        const float w0 = wp[0], w1 = wp[1], w2 = wp[2];
                        const float w3 = wp[3], w4 = wp[4], w5 = wp[5];
                        const float w6 = wp[6], w7 = wp[7], w8 = wp[8];
#pragma unroll
                        for (int r = 0; r < 4; ++r) {
                            float a = acc[r][k];
                            a = fmaf(xv[r + 0][0], w0, a);
                            a = fmaf(xv[r + 0][1], w1, a);
                            a = fmaf(xv[r + 0][2], w2, a);
                            a = fmaf(xv[r + 1][0], w3, a);
                            a = fmaf(xv[r + 1][1], w4, a);
                            a = fmaf(xv[r + 1][2], w5, a);
                            a = fmaf(xv[r + 2][0], w6, a);
                            a = fmaf(xv[r + 2][1], w7, a);
                            a = fmaf(xv[r + 2][2], w8, a);
                            acc[r][k] = a;
                        }
                    }
                }
            }
        }
        if (col < 56) {
#pragma unroll
            for (int k = 0; k < 16; ++k) {
                if (k < kmax) {
                    const int ol = ocq + 4 * k;
                    const int f  = meta[META_FLIST + fbas + oc0 + ol];
                    const int ch = meta[META_DEST + f];
#pragma unroll
                    for (int r = 0; r < 4; ++r)
                        out[((b * 256 + ch) * 56 + (h0 + r)) * 56 + col] = acc[r][k];
                }
            }
        }
    }
}

extern "C" void kernel_launch(void* const* d_in, const int* in_sizes, int n_in,
                              void* d_out, int out_size, void* d_ws, size_t ws_size,
                              hipStream_t stream) {
    const float* x    = (const float*)d_in[0];   // [32,256,56,56]
    const float* conv = (const float*)d_in[1];   // [256,256,3,3]
    const float* S    = (const float*)d_in[2];   // [256,8]
    const float* T    = (const float*)d_in[3];   // [256,8]
    float* out = (float*)d_out;                  // [32,256,56,56]
    int*   meta  = (int*)d_ws;
    float* wpack = (float*)d_ws + META_WPACK;

    flgc_setup<<<1, 256, 0, stream>>>(S, T, meta);
    flgc_pack<<<512, 256, 0, stream>>>(conv, meta, wpack);
    dim3 grid(14, 32, 8);   // 14 row-stripes x 32 batch x 8 groups
    flgc_conv<<<grid, 256, 0, stream>>>(x, meta, wpack, out);
}

// Round 2
// 213.446 us; speedup vs baseline: 2.1466x; 2.1466x over previous
//
#include <hip/hip_runtime.h>

// ---------------- meta layout in d_ws, units of 4 bytes ----------------
#define M_SI    0      // f32[256] softmax max-prob per input channel
#define M_SO    256    // f32[256] per filter
#define M_CLIST 512    // i32[256] input channels, group-major stable
#define M_FLIST 768    // i32[256] filters, group-major stable (= perm)
#define M_DEST  1024   // i32[256] dest[f] = output channel for filter f
#define M_CBASE 1280   // i32[8]
#define M_FBASE 1288   // i32[8]
#define M_CCNT  1296   // i32[8]
#define M_FCNT  1304   // i32[8]
#define M_WOFFE 1312   // i32[9] element offsets into wpack, [8]=total
#define WPACK_BYTE_OFF 16384

typedef short bf16x8 __attribute__((ext_vector_type(8)));
typedef float f32x4  __attribute__((ext_vector_type(4)));

__device__ __forceinline__ unsigned short f2bf(float f) {
    unsigned u = __float_as_uint(f);
    u += 0x7fffu + ((u >> 16) & 1u);
    return (unsigned short)(u >> 16);
}

__global__ __launch_bounds__(256) void flgc_setup(const float* __restrict__ S,
                                                  const float* __restrict__ T,
                                                  int* __restrict__ meta) {
    __shared__ float si[256], so[256];
    __shared__ int gin[256], gout[256];
    __shared__ int cnt_in[8], cnt_out[8], cb[8], fb[8];
    __shared__ int perm[256], destl[256];
    const int c = threadIdx.x;  // 0..255

    {   // softmax max-prob + argmax (first occurrence) for S row c
        float m = S[c * 8]; int am = 0;
        for (int k = 1; k < 8; ++k) { float v = S[c * 8 + k]; if (v > m) { m = v; am = k; } }
        float s = 0.f;
        for (int k = 0; k < 8; ++k) s += expf(S[c * 8 + k] - m);
        si[c] = 1.0f / s; gin[c] = am;
    }
    {
        float m = T[c * 8]; int am = 0;
        for (int k = 1; k < 8; ++k) { float v = T[c * 8 + k]; if (v > m) { m = v; am = k; } }
        float s = 0.f;
        for (int k = 0; k < 8; ++k) s += expf(T[c * 8 + k] - m);
        so[c] = 1.0f / s; gout[c] = am;
    }
    __syncthreads();
    const int g = gin[c], go = gout[c];
    int r1 = 0, r2 = 0;  // stable rank within group
    for (int i = 0; i < c; ++i) { r1 += (gin[i] == g); r2 += (gout[i] == go); }
    if (c < 8) {
        int n1 = 0, n2 = 0;
        for (int i = 0; i < 256; ++i) { n1 += (gin[i] == c); n2 += (gout[i] == c); }
        cnt_in[c] = n1; cnt_out[c] = n2;
    }
    __syncthreads();
    if (c == 0) {
        int a = 0, b = 0;
        for (int k = 0; k < 8; ++k) { cb[k] = a; a += cnt_in[k]; fb[k] = b; b += cnt_out[k]; }
    }
    __syncthreads();
    meta[M_CLIST + cb[g] + r1] = c;
    perm[fb[go] + r2] = c;               // = argsort(t stable)
    __syncthreads();
    const int ppc = perm[perm[c]];       // pp[j], j = c
    destl[ppc] = c;                      // dest[pp[j]] = j
    __syncthreads();
    ((float*)meta)[M_SI + c] = si[c];
    ((float*)meta)[M_SO + c] = so[c];
    meta[M_FLIST + c] = perm[c];
    meta[M_DEST + c]  = destl[c];
    if (c < 8) {
        meta[M_CBASE + c] = cb[c];
        meta[M_FBASE + c] = fb[c];
        meta[M_CCNT + c]  = cnt_in[c];
        meta[M_FCNT + c]  = cnt_out[c];
    }
    if (c == 0) {
        int a = 0;
        for (int k = 0; k < 8; ++k) {
            meta[M_WOFFE + k] = a;
            const int nq  = (cnt_in[k] + 31) >> 5;
            const int mfa = (cnt_out[k] + 15) >> 4;
            a += nq * mfa * 9 * 512;
        }
        meta[M_WOFFE + 8] = a;
    }
}

// wpack: per group, [q][mf][tap][lane 0..63][j 0..7] bf16 in exact A-fragment
// lane order for mfma_f32_16x16x32_bf16: f = mf*16 + (lane&15), c = q*32 + (lane>>4)*8 + j.
// Scales si*so folded in; zero-padded beyond fcnt/ccnt.
__global__ void flgc_pack(const float* __restrict__ conv, const int* __restrict__ meta,
                          unsigned short* __restrict__ wpack) {
    const float* si = (const float*)meta + M_SI;
    const float* so = (const float*)meta + M_SO;
    const int total = meta[M_WOFFE + 8];
    for (int idx = blockIdx.x * blockDim.x + threadIdx.x; idx < total;
         idx += gridDim.x * blockDim.x) {
        int gg = 0;
        while (gg < 7 && idx >= meta[M_WOFFE + gg + 1]) ++gg;
        const int local = idx - meta[M_WOFFE + gg];
        const int fcnt = meta[M_FCNT + gg], ccnt = meta[M_CCNT + gg];
        const int mfall = (fcnt + 15) >> 4;
        const int fragidx = local >> 9, e = local & 511;
        const int lane = e >> 3, j = e & 7;
        const int tap = fragidx % 9, t2 = fragidx / 9;
        const int mf = t2 % mfall, q = t2 / mfall;
        const int fl = mf * 16 + (lane & 15);
        const int cl = q * 32 + (lane >> 4) * 8 + j;
        float v = 0.f;
        if (fl < fcnt && cl < ccnt) {
            const int F  = meta[M_FLIST + meta[M_FBASE + gg] + fl];
            const int CH = meta[M_CLIST + meta[M_CBASE + gg] + cl];
            v = conv[(F * 256 + CH) * 9 + tap] * si[CH] * so[F];
        }
        wpack[idx] = f2bf(v);
    }
}

// MFMA implicit-GEMM grouped conv.
// Block = (group, batch, 8-row stripe). 4 waves; wave w owns rows {2w,2w+1} x 56 cols.
// x tile LDS: [row 0..9][kg 0..3][col 0..63][8 chans] bf16 (col = image col + 1).
// B frag (16 px = 2 rows x 8 cols) = one ds_read_b128, bank-uniform.
__global__ __launch_bounds__(256, 2) void flgc_conv_mfma(const float* __restrict__ x,
                                                         const int* __restrict__ meta,
                                                         const unsigned short* __restrict__ wpack,
                                                         float* __restrict__ out) {
    __shared__ __align__(16) unsigned short xlds[10 * 4 * 64 * 8];  // 40 KB
    __shared__ __align__(16) unsigned short wlds[4 * 9 * 512];      // 36 KB
    const int g = blockIdx.z, b = blockIdx.y, h0 = blockIdx.x * 8;
    const int tid = threadIdx.x, lane = tid & 63, wv = tid >> 6;
    const int ccnt = meta[M_CCNT + g], fcnt = meta[M_FCNT + g];
    const int cbas = meta[M_CBASE + g], fbas = meta[M_FBASE + g];
    const int woffe = meta[M_WOFFE + g];
    const int nq = (ccnt + 31) >> 5, mfall = (fcnt + 15) >> 4;
    if (mfall == 0) return;
    const int n = lane & 15, kgl = lane >> 4;
    const int prow = 2 * wv + (n >> 3);   // wave's output row within stripe (per lane half)
    const int pcol = n & 7;

    for (int mf0 = 0; mf0 < mfall; mf0 += 4) {
        const int mfe = min(4, mfall - mf0);
        f32x4 acc[4][7];
#pragma unroll
        for (int mf = 0; mf < 4; ++mf)
#pragma unroll
            for (int cg = 0; cg < 7; ++cg) acc[mf][cg] = (f32x4){0.f, 0.f, 0.f, 0.f};

        for (int q = 0; q < nq; ++q) {
            __syncthreads();
            // ---- stage A fragments (bf16, pre-packed lane order) ----
            for (int widx = wv; widx < mfe * 9; widx += 4) {
                const int mf = widx / 9, tap = widx - mf * 9;
                const unsigned short* src =
                    wpack + woffe + (((q * mfall) + mf0 + mf) * 9 + tap) * 512 + lane * 8;
                *(bf16x8*)&wlds[(mf * 9 + tap) * 512 + lane * 8] = *(const bf16x8*)src;
            }
            // ---- stage x tile: gather fp32 NCHW -> bf16 chan-interleaved LDS ----
            // i -> (colx = i&63, rr = (i>>6)>>3, cq = (i>>6)&7); 4 chans per thread.
            for (int i = tid; i < 80 * 64; i += 256) {
                const int colx = i & 63, t = i >> 6;
                const int rr = t >> 3, cq = t & 7;
                const int c0 = q * 32 + cq * 4;
                const int row = h0 + rr - 1, ic = colx - 1;
                float v0 = 0.f, v1 = 0.f, v2 = 0.f, v3 = 0.f;
                if ((unsigned)row < 56u && (unsigned)ic < 56u) {
                    const float* xp = x + (size_t)(b * 256) * 3136 + row * 56 + ic;
                    if (c0 + 0 < ccnt) v0 = xp[(size_t)meta[M_CLIST + cbas + c0 + 0] * 3136];
                    if (c0 + 1 < ccnt) v1 = xp[(size_t)meta[M_CLIST + cbas + c0 + 1] * 3136];
                    if (c0 + 2 < ccnt) v2 = xp[(size_t)meta[M_CLIST + cbas + c0 + 2] * 3136];
                    if (c0 + 3 < ccnt) v3 = xp[(size_t)meta[M_CLIST + cbas + c0 + 3] * 3136];
                }
                ushort4 pk = make_ushort4(f2bf(v0), f2bf(v1), f2bf(v2), f2bf(v3));
                *(ushort4*)&xlds[(((rr * 4 + (cq >> 1)) * 64 + colx) << 3) + ((cq & 1) << 2)] = pk;
            }
            __syncthreads();
            // ---- 9 shifted GEMMs ----
#pragma unroll
            for (int tap = 0; tap < 9; ++tap) {
                const int dr = tap / 3, dcp = tap - dr * 3;   // dcp = kw (0..2)
                bf16x8 A[4];
#pragma unroll
                for (int mf = 0; mf < 4; ++mf)
                    if (mf < mfe)
                        A[mf] = *(bf16x8*)&wlds[(mf * 9 + tap) * 512 + lane * 8];
                const int row_r = prow + dr;                   // 0..9
                const int xbase = ((row_r * 4 + kgl) * 64) << 3;
#pragma unroll
                for (int cg = 0; cg < 7; ++cg) {
                    const int cc = cg * 8 + pcol + dcp;        // LDS col = image col + kw
                    const bf16x8 B = *(bf16x8*)&xlds[xbase + (cc << 3)];
#pragma unroll
                    for (int mf = 0; mf < 4; ++mf)
                        if (mf < mfe)
                            acc[mf][cg] = __builtin_amdgcn_mfma_f32_16x16x32_bf16(
                                A[mf], B, acc[mf][cg], 0, 0, 0);
                }
            }
        }
        // ---- epilogue: C frag col = lane&15 (pixel), row = (lane>>4)*4 + reg (filter) ----
#pragma unroll
        for (int mf = 0; mf < 4; ++mf) {
            if (mf < mfe) {
#pragma unroll
                for (int reg = 0; reg < 4; ++reg) {
                    const int fl = (mf0 + mf) * 16 + (lane >> 4) * 4 + reg;
                    if (fl < fcnt) {
                        const int F  = meta[M_FLIST + fbas + fl];
                        const int oc = meta[M_DEST + F];
                        float* op = out + ((size_t)(b * 256 + oc) * 56 + (h0 + prow)) * 56 + pcol;
#pragma unroll
                        for (int cg = 0; cg < 7; ++cg)
                            op[cg * 8] = acc[mf][cg][reg];
                    }
                }
            }
        }
    }
}

extern "C" void kernel_launch(void* const* d_in, const int* in_sizes, int n_in,
                              void* d_out, int out_size, void* d_ws, size_t ws_size,
                              hipStream_t stream) {
    const float* x    = (const float*)d_in[0];   // [32,256,56,56]
    const float* conv = (const float*)d_in[1];   // [256,256,3,3]
    const float* S    = (const float*)d_in[2];   // [256,8]
    const float* T    = (const float*)d_in[3];   // [256,8]
    float* out = (float*)d_out;                  // [32,256,56,56]
    int* meta = (int*)d_ws;
    unsigned short* wpack = (unsigned short*)((char*)d_ws + WPACK_BYTE_OFF);

    flgc_setup<<<1, 256, 0, stream>>>(S, T, meta);
    flgc_pack<<<256, 256, 0, stream>>>(conv, meta, wpack);
    dim3 grid(7, 32, 8);   // 7 row-stripes x 32 batch x 8 groups
    flgc_conv_mfma<<<grid, 256, 0, stream>>>(x, meta, wpack, out);
}

// Round 3
// 152.667 us; speedup vs baseline: 3.0012x; 1.3981x over previous
//
#include <hip/hip_runtime.h>

// ---------------- meta layout in d_ws, units of 4 bytes ----------------
#define M_SI    0      // f32[256] softmax max-prob per input channel
#define M_SO    256    // f32[256] per filter
#define M_CLIST 512    // i32[256] input channels, group-major stable
#define M_FLIST 768    // i32[256] filters, group-major stable (= perm)
#define M_DEST  1024   // i32[256] dest[f] = output channel for filter f
#define M_CBASE 1280   // i32[8]
#define M_FBASE 1288   // i32[8]
#define M_CCNT  1296   // i32[8]
#define M_FCNT  1304   // i32[8]
#define M_WOFFE 1312   // i32[9] element offsets into wpack, [8]=total
#define WPACK_BYTE_OFF 16384
#define XR_BYTE_OFF   (4u << 20)          // 4 MB
#define SLOT_ELEMS    3444736ull          // 32 b * 58*58 * 32 ch (bf16 elems)
#define SLOT_BYTES    (SLOT_ELEMS * 2ull)

typedef short bf16x8 __attribute__((ext_vector_type(8)));
typedef float f32x4  __attribute__((ext_vector_type(4)));

__device__ __forceinline__ unsigned short f2bf(float f) {
    unsigned u = __float_as_uint(f);
    u += 0x7fffu + ((u >> 16) & 1u);
    return (unsigned short)(u >> 16);
}

__device__ __forceinline__ void gl_lds16(const void* g, void* l) {
    __builtin_amdgcn_global_load_lds((const __attribute__((address_space(1))) unsigned int*)g,
                                     (__attribute__((address_space(3))) unsigned int*)l, 16, 0, 0);
}

__global__ __launch_bounds__(256) void flgc_setup(const float* __restrict__ S,
                                                  const float* __restrict__ T,
                                                  int* __restrict__ meta) {
    __shared__ float si[256], so[256];
    __shared__ int gin[256], gout[256];
    __shared__ int cnt_in[8], cnt_out[8], cb[8], fb[8];
    __shared__ int perm[256], destl[256];
    const int c = threadIdx.x;  // 0..255

    {   // softmax max-prob + argmax (first occurrence) for S row c
        float m = S[c * 8]; int am = 0;
        for (int k = 1; k < 8; ++k) { float v = S[c * 8 + k]; if (v > m) { m = v; am = k; } }
        float s = 0.f;
        for (int k = 0; k < 8; ++k) s += expf(S[c * 8 + k] - m);
        si[c] = 1.0f / s; gin[c] = am;
    }
    {
        float m = T[c * 8]; int am = 0;
        for (int k = 1; k < 8; ++k) { float v = T[c * 8 + k]; if (v > m) { m = v; am = k; } }
        float s = 0.f;
        for (int k = 0; k < 8; ++k) s += expf(T[c * 8 + k] - m);
        so[c] = 1.0f / s; gout[c] = am;
    }
    __syncthreads();
    const int g = gin[c], go = gout[c];
    int r1 = 0, r2 = 0;  // stable rank within group
    for (int i = 0; i < c; ++i) { r1 += (gin[i] == g); r2 += (gout[i] == go); }
    if (c < 8) {
        int n1 = 0, n2 = 0;
        for (int i = 0; i < 256; ++i) { n1 += (gin[i] == c); n2 += (gout[i] == c); }
        cnt_in[c] = n1; cnt_out[c] = n2;
    }
    __syncthreads();
    if (c == 0) {
        int a = 0, b = 0;
        for (int k = 0; k < 8; ++k) { cb[k] = a; a += cnt_in[k]; fb[k] = b; b += cnt_out[k]; }
    }
    __syncthreads();
    meta[M_CLIST + cb[g] + r1] = c;
    perm[fb[go] + r2] = c;               // = argsort(t stable)
    __syncthreads();
    const int ppc = perm[perm[c]];       // pp[j], j = c
    destl[ppc] = c;                      // dest[pp[j]] = j
    __syncthreads();
    ((float*)meta)[M_SI + c] = si[c];
    ((float*)meta)[M_SO + c] = so[c];
    meta[M_FLIST + c] = perm[c];
    meta[M_DEST + c]  = destl[c];
    if (c < 8) {
        meta[M_CBASE + c] = cb[c];
        meta[M_FBASE + c] = fb[c];
        meta[M_CCNT + c]  = cnt_in[c];
        meta[M_FCNT + c]  = cnt_out[c];
    }
    if (c == 0) {
        int a = 0;
        for (int k = 0; k < 8; ++k) {
            meta[M_WOFFE + k] = a;
            const int nq  = (cnt_in[k] + 31) >> 5;
            const int mfa = (cnt_out[k] + 15) >> 4;
            a += nq * mfa * 9 * 512;
        }
        meta[M_WOFFE + 8] = a;
    }
}

// wpack: per group, [q][mf][tap][lane 0..63][j 0..7] bf16 in exact A-fragment
// lane order for mfma_f32_16x16x32_bf16: f = mf*16 + (lane&15), c = q*32 + (lane>>4)*8 + j.
// Scales si*so folded in; zero-padded beyond fcnt/ccnt.
__global__ void flgc_pack(const float* __restrict__ conv, const int* __restrict__ meta,
                          unsigned short* __restrict__ wpack) {
    const float* si = (const float*)meta + M_SI;
    const float* so = (const float*)meta + M_SO;
    const int total = meta[M_WOFFE + 8];
    for (int idx = blockIdx.x * blockDim.x + threadIdx.x; idx < total;
         idx += gridDim.x * blockDim.x) {
        int gg = 0;
        while (gg < 7 && idx >= meta[M_WOFFE + gg + 1]) ++gg;
        const int local = idx - meta[M_WOFFE + gg];
        const int fcnt = meta[M_FCNT + gg], ccnt = meta[M_CCNT + gg];
        const int mfall = (fcnt + 15) >> 4;
        const int fragidx = local >> 9, e = local & 511;
        const int lane = e >> 3, j = e & 7;
        const int tap = fragidx % 9, t2 = fragidx / 9;
        const int mf = t2 % mfall, q = t2 / mfall;
        const int fl = mf * 16 + (lane & 15);
        const int cl = q * 32 + (lane >> 4) * 8 + j;
        float v = 0.f;
        if (fl < fcnt && cl < ccnt) {
            const int F  = meta[M_FLIST + meta[M_FBASE + gg] + fl];
            const int CH = meta[M_CLIST + meta[M_CBASE + gg] + cl];
            v = conv[(F * 256 + CH) * 9 + tap] * si[CH] * so[F];
        }
        wpack[idx] = f2bf(v);
    }
}

// ---- fast path: reorder x into xr[g*2+q][b][row 0..57][col 0..57][cl 0..31] bf16,
// rows/cols shifted +1 with zero halo border; channels group-gathered, bf16-converted.
__global__ __launch_bounds__(256) void flgc_reorder(const float* __restrict__ x,
                                                    const int* __restrict__ meta,
                                                    unsigned short* __restrict__ xr) {
    __shared__ float lds[32][65];
    const int r = blockIdx.x;           // xr row 0..57
    const int b = blockIdx.y;
    const int slot = blockIdx.z;        // g*2+q
    const int g = slot >> 1, q = slot & 1;
    const int ccnt = meta[M_CCNT + g];
    int nq = (ccnt + 31) >> 5; if (nq > 2) nq = 2;
    if (q >= nq) return;
    const int cbas = meta[M_CBASE + g];
    const int row = r - 1;
    for (int j = threadIdx.x; j < 32 * 64; j += 256) {
        const int cl = j >> 6, colx = j & 63;
        const int ic = colx - 1, cgl = q * 32 + cl;
        float v = 0.f;
        if (cgl < ccnt && (unsigned)row < 56u && (unsigned)ic < 56u)
            v = x[((size_t)(b * 256 + meta[M_CLIST + cbas + cgl])) * 3136 + row * 56 + ic];
        lds[cl][colx] = v;
    }
    __syncthreads();
    unsigned short* dst = xr + (size_t)(slot * 32 + b) * 107648ull + r * 58 * 32;
    for (int i = threadIdx.x; i < 58 * 16; i += 256) {
        const int col = i >> 4, cl2 = (i & 15) * 2;
        ushort2 pk = make_ushort2(f2bf(lds[cl2][col]), f2bf(lds[cl2 + 1][col]));
        *(ushort2*)&dst[col * 32 + cl2] = pk;
    }
}

// ---- fast path conv: block=(stripe,b,g); 4 waves; tile staged via global_load_lds.
// LDS x tile: [row 0..9][col 0..57][cl 0..31] bf16 = 37120 B (alloc 37888 incl. slack).
__global__ __launch_bounds__(256, 2) void flgc_conv_f(const int* __restrict__ meta,
                                                      const unsigned short* __restrict__ wpack,
                                                      const unsigned short* __restrict__ xr,
                                                      float* __restrict__ out) {
    __shared__ __align__(16) unsigned short xbuf[18944];   // 37888 B
    __shared__ __align__(16) unsigned short wbuf[13824];   // 27648 B (3 mf x 9 taps x 512)
    const int g = blockIdx.z, b = blockIdx.y, h0 = blockIdx.x * 8;
    const int tid = threadIdx.x, lane = tid & 63, wv = tid >> 6;
    const int ccnt = meta[M_CCNT + g], fcnt = meta[M_FCNT + g];
    const int fbas = meta[M_FBASE + g];
    const int woffe = meta[M_WOFFE + g];
    int nq = (ccnt + 31) >> 5; if (nq > 2) nq = 2;
    const int mfall = (fcnt + 15) >> 4;
    if (mfall == 0) return;
    const int n = lane & 15, kg = lane >> 4;
    const int prow = 2 * wv + (n >> 3), pcol = n & 7;

    for (int mf0 = 0; mf0 < mfall; mf0 += 3) {
        const int mfe = min(3, mfall - mf0);
        f32x4 acc[3][7];
#pragma unroll
        for (int mf = 0; mf < 3; ++mf)
#pragma unroll
            for (int cg = 0; cg < 7; ++cg) acc[mf][cg] = (f32x4){0.f, 0.f, 0.f, 0.f};

        for (int q = 0; q < nq; ++q) {
            __syncthreads();
            // x tile: 37 x 1KB wave-calls (768B tail slack covered by xr over-alloc)
            const char* tbase = (const char*)(xr + (size_t)((g * 2 + q) * 32 + b) * 107648ull
                                              + (size_t)h0 * 58 * 32);
            for (int k = wv; k < 37; k += 4)
                gl_lds16(tbase + k * 1024 + lane * 16, (char*)xbuf + k * 1024);
            // weight fragments for this (q, mf-block): mfe*9 x 1KB wave-calls
            const char* wsrc = (const char*)(wpack + woffe + (size_t)(q * mfall + mf0) * 9 * 512);
            for (int k = wv; k < mfe * 9; k += 4)
                gl_lds16(wsrc + k * 1024 + lane * 16, (char*)wbuf + k * 1024);
            __syncthreads();   // drains vmcnt(0) before barrier (compiler-enforced)
#pragma unroll
            for (int tap = 0; tap < 9; ++tap) {
                const int dr = tap / 3, dc = tap - dr * 3;
                bf16x8 A[3];
#pragma unroll
                for (int mf = 0; mf < 3; ++mf)
                    if (mf < mfe)
                        A[mf] = *(bf16x8*)&wbuf[(mf * 9 + tap) * 512 + lane * 8];
                const int rb = (prow + dr) * 58;
#pragma unroll
                for (int cg = 0; cg < 7; ++cg) {
                    const int colx = pcol + cg * 8 + dc;
                    const bf16x8 B = *(bf16x8*)&xbuf[(rb + colx) * 32 + kg * 8];
#pragma unroll
                    for (int mf = 0; mf < 3; ++mf)
                        if (mf < mfe)
                            acc[mf][cg] = __builtin_amdgcn_mfma_f32_16x16x32_bf16(
                                A[mf], B, acc[mf][cg], 0, 0, 0);
                }
            }
        }
        // epilogue: C frag col = lane&15 (pixel), row = (lane>>4)*4 + reg (filter)
#pragma unroll
        for (int mf = 0; mf < 3; ++mf) {
            if (mf < mfe) {
#pragma unroll
                for (int reg = 0; reg < 4; ++reg) {
                    const int fl = (mf0 + mf) * 16 + (lane >> 4) * 4 + reg;
                    if (fl < fcnt) {
                        const int F  = meta[M_FLIST + fbas + fl];
                        const int oc = meta[M_DEST + F];
                        float* op = out + ((size_t)(b * 256 + oc) * 56 + (h0 + prow)) * 56 + pcol;
#pragma unroll
                        for (int cg = 0; cg < 7; ++cg)
                            op[cg * 8] = acc[mf][cg][reg];
                    }
                }
            }
        }
    }
}

// ---- fallback (small ws): round-2 direct-gather MFMA kernel, known-good.
__global__ __launch_bounds__(256, 2) void flgc_conv_mfma(const float* __restrict__ x,
                                                         const int* __restrict__ meta,
                                                         const unsigned short* __restrict__ wpack,
                                                         float* __restrict__ out) {
    __shared__ __align__(16) unsigned short xlds[10 * 4 * 64 * 8];
    __shared__ __align__(16) unsigned short wlds[4 * 9 * 512];
    const int g = blockIdx.z, b = blockIdx.y, h0 = blockIdx.x * 8;
    const int tid = threadIdx.x, lane = tid & 63, wv = tid >> 6;
    const int ccnt = meta[M_CCNT + g], fcnt = meta[M_FCNT + g];
    const int cbas = meta[M_CBASE + g], fbas = meta[M_FBASE + g];
    const int woffe = meta[M_WOFFE + g];
    const int nq = (ccnt + 31) >> 5, mfall = (fcnt + 15) >> 4;
    if (mfall == 0) return;
    const int n = lane & 15, kgl = lane >> 4;
    const int prow = 2 * wv + (n >> 3);
    const int pcol = n & 7;

    for (int mf0 = 0; mf0 < mfall; mf0 += 4) {
        const int mfe = min(4, mfall - mf0);
        f32x4 acc[4][7];
#pragma unroll
        for (int mf = 0; mf < 4; ++mf)
#pragma unroll
            for (int cg = 0; cg < 7; ++cg) acc[mf][cg] = (f32x4){0.f, 0.f, 0.f, 0.f};

        for (int q = 0; q < nq; ++q) {
            __syncthreads();
            for (int widx = wv; widx < mfe * 9; widx += 4) {
                const int mf = widx / 9, tap = widx - mf * 9;
                const unsigned short* src =
                    wpack + woffe + (((q * mfall) + mf0 + mf) * 9 + tap) * 512 + lane * 8;
                *(bf16x8*)&wlds[(mf * 9 + tap) * 512 + lane * 8] = *(const bf16x8*)src;
            }
            for (int i = tid; i < 80 * 64; i += 256) {
                const int colx = i & 63, t = i >> 6;
                const int rr = t >> 3, cq = t & 7;
                const int c0 = q * 32 + cq * 4;
                const int row = h0 + rr - 1, ic = colx - 1;
                float v0 = 0.f, v1 = 0.f, v2 = 0.f, v3 = 0.f;
                if ((unsigned)row < 56u && (unsigned)ic < 56u) {
                    const float* xp = x + (size_t)(b * 256) * 3136 + row * 56 + ic;
                    if (c0 + 0 < ccnt) v0 = xp[(size_t)meta[M_CLIST + cbas + c0 + 0] * 3136];
                    if (c0 + 1 < ccnt) v1 = xp[(size_t)meta[M_CLIST + cbas + c0 + 1] * 3136];
                    if (c0 + 2 < ccnt) v2 = xp[(size_t)meta[M_CLIST + cbas + c0 + 2] * 3136];
                    if (c0 + 3 < ccnt) v3 = xp[(size_t)meta[M_CLIST + cbas + c0 + 3] * 3136];
                }
                ushort4 pk = make_ushort4(f2bf(v0), f2bf(v1), f2bf(v2), f2bf(v3));
                *(ushort4*)&xlds[(((rr * 4 + (cq >> 1)) * 64 + colx) << 3) + ((cq & 1) << 2)] = pk;
            }
            __syncthreads();
#pragma unroll
            for (int tap = 0; tap < 9; ++tap) {
                const int dr = tap / 3, dcp = tap - dr * 3;
                bf16x8 A[4];
#pragma unroll
                for (int mf = 0; mf < 4; ++mf)
                    if (mf < mfe)
                        A[mf] = *(bf16x8*)&wlds[(mf * 9 + tap) * 512 + lane * 8];
                const int row_r = prow + dr;
                const int xbase = ((row_r * 4 + kgl) * 64) << 3;
#pragma unroll
                for (int cg = 0; cg < 7; ++cg) {
                    const int cc = cg * 8 + pcol + dcp;
                    const bf16x8 B = *(bf16x8*)&xlds[xbase + (cc << 3)];
#pragma unroll
                    for (int mf = 0; mf < 4; ++mf)
                        if (mf < mfe)
                            acc[mf][cg] = __builtin_amdgcn_mfma_f32_16x16x32_bf16(
                                A[mf], B, acc[mf][cg], 0, 0, 0);
                }
            }
        }
#pragma unroll
        for (int mf = 0; mf < 4; ++mf) {
            if (mf < mfe) {
#pragma unroll
                for (int reg = 0; reg < 4; ++reg) {
                    const int fl = (mf0 + mf) * 16 + (lane >> 4) * 4 + reg;
                    if (fl < fcnt) {
                        const int F  = meta[M_FLIST + fbas + fl];
                        const int oc = meta[M_DEST + F];
                        float* op = out + ((size_t)(b * 256 + oc) * 56 + (h0 + prow)) * 56 + pcol;
#pragma unroll
                        for (int cg = 0; cg < 7; ++cg)
                            op[cg * 8] = acc[mf][cg][reg];
                    }
                }
            }
        }
    }
}

extern "C" void kernel_launch(void* const* d_in, const int* in_sizes, int n_in,
                              void* d_out, int out_size, void* d_ws, size_t ws_size,
                              hipStream_t stream) {
    const float* x    = (const float*)d_in[0];   // [32,256,56,56]
    const float* conv = (const float*)d_in[1];   // [256,256,3,3]
    const float* S    = (const float*)d_in[2];   // [256,8]
    const float* T    = (const float*)d_in[3];   // [256,8]
    float* out = (float*)d_out;                  // [32,256,56,56]
    int* meta = (int*)d_ws;
    unsigned short* wpack = (unsigned short*)((char*)d_ws + WPACK_BYTE_OFF);
    unsigned short* xr    = (unsigned short*)((char*)d_ws + XR_BYTE_OFF);

    flgc_setup<<<1, 256, 0, stream>>>(S, T, meta);
    flgc_pack<<<256, 256, 0, stream>>>(conv, meta, wpack);

    const size_t need = (size_t)XR_BYTE_OFF + 16ull * SLOT_BYTES + 4096;
    if (ws_size >= need) {
        flgc_reorder<<<dim3(58, 32, 16), 256, 0, stream>>>(x, meta, xr);
        flgc_conv_f<<<dim3(7, 32, 8), 256, 0, stream>>>(meta, wpack, xr, out);
    } else {
        flgc_conv_mfma<<<dim3(7, 32, 8), 256, 0, stream>>>(x, meta, wpack, out);
    }
}

// Round 4
// 116.031 us; speedup vs baseline: 3.9488x; 1.3157x over previous
//
#include <hip/hip_runtime.h>

// ---------------- meta layout in d_ws, units of 4 bytes ----------------
#define M_SI    0      // f32[256] softmax max-prob per input channel
#define M_SO    256    // f32[256] per filter
#define M_CLIST 512    // i32[256] input channels, group-major stable
#define M_FLIST 768    // i32[256] filters, group-major stable (= perm)
#define M_DEST  1024   // i32[256] dest[f] = output channel for filter f
#define M_CBASE 1280   // i32[8]
#define M_FBASE 1288   // i32[8]
#define M_CCNT  1296   // i32[8]
#define M_FCNT  1304   // i32[8]
#define M_WOFFE 1312   // i32[9] element offsets into wpack, [8]=total
#define WPACK_BYTE_OFF 16384
#define XR_BYTE_OFF   (4u << 20)          // 4 MB
#define SLOT_ELEMS    3444736ull          // 32 b * 58*58 * 32 ch (bf16 elems)
#define SLOT_BYTES    (SLOT_ELEMS * 2ull)

typedef short bf16x8 __attribute__((ext_vector_type(8)));
typedef float f32x4  __attribute__((ext_vector_type(4)));

__device__ __forceinline__ unsigned short f2bf(float f) {
    unsigned u = __float_as_uint(f);
    u += 0x7fffu + ((u >> 16) & 1u);
    return (unsigned short)(u >> 16);
}

__device__ __forceinline__ void gl_lds16(const void* g, void* l) {
    __builtin_amdgcn_global_load_lds((const __attribute__((address_space(1))) unsigned int*)g,
                                     (__attribute__((address_space(3))) unsigned int*)l, 16, 0, 0);
}

__global__ __launch_bounds__(256) void flgc_setup(const float* __restrict__ S,
                                                  const float* __restrict__ T,
                                                  int* __restrict__ meta) {
    __shared__ float si[256], so[256];
    __shared__ int gin[256], gout[256];
    __shared__ int cnt_in[8], cnt_out[8], cb[8], fb[8];
    __shared__ int perm[256], destl[256];
    const int c = threadIdx.x;  // 0..255

    {   // softmax max-prob + argmax (first occurrence) for S row c
        float m = S[c * 8]; int am = 0;
        for (int k = 1; k < 8; ++k) { float v = S[c * 8 + k]; if (v > m) { m = v; am = k; } }
        float s = 0.f;
        for (int k = 0; k < 8; ++k) s += expf(S[c * 8 + k] - m);
        si[c] = 1.0f / s; gin[c] = am;
    }
    {
        float m = T[c * 8]; int am = 0;
        for (int k = 1; k < 8; ++k) { float v = T[c * 8 + k]; if (v > m) { m = v; am = k; } }
        float s = 0.f;
        for (int k = 0; k < 8; ++k) s += expf(T[c * 8 + k] - m);
        so[c] = 1.0f / s; gout[c] = am;
    }
    __syncthreads();
    const int g = gin[c], go = gout[c];
    int r1 = 0, r2 = 0;  // stable rank within group
    for (int i = 0; i < c; ++i) { r1 += (gin[i] == g); r2 += (gout[i] == go); }
    if (c < 8) {
        int n1 = 0, n2 = 0;
        for (int i = 0; i < 256; ++i) { n1 += (gin[i] == c); n2 += (gout[i] == c); }
        cnt_in[c] = n1; cnt_out[c] = n2;
    }
    __syncthreads();
    if (c == 0) {
        int a = 0, b = 0;
        for (int k = 0; k < 8; ++k) { cb[k] = a; a += cnt_in[k]; fb[k] = b; b += cnt_out[k]; }
    }
    __syncthreads();
    meta[M_CLIST + cb[g] + r1] = c;
    perm[fb[go] + r2] = c;               // = argsort(t stable)
    __syncthreads();
    const int ppc = perm[perm[c]];       // pp[j], j = c
    destl[ppc] = c;                      // dest[pp[j]] = j
    __syncthreads();
    ((float*)meta)[M_SI + c] = si[c];
    ((float*)meta)[M_SO + c] = so[c];
    meta[M_FLIST + c] = perm[c];
    meta[M_DEST + c]  = destl[c];
    if (c < 8) {
        meta[M_CBASE + c] = cb[c];
        meta[M_FBASE + c] = fb[c];
        meta[M_CCNT + c]  = cnt_in[c];
        meta[M_FCNT + c]  = cnt_out[c];
    }
    if (c == 0) {
        int a = 0;
        for (int k = 0; k < 8; ++k) {
            meta[M_WOFFE + k] = a;
            const int nq  = (cnt_in[k] + 31) >> 5;
            const int mfa = (cnt_out[k] + 15) >> 4;
            a += nq * mfa * 9 * 512;
        }
        meta[M_WOFFE + 8] = a;
    }
}

// wpack: per group, [q][mf][tap][lane 0..63][j 0..7] bf16 in exact A-fragment
// lane order for mfma_f32_16x16x32_bf16: f = mf*16 + (lane&15), c = q*32 + (lane>>4)*8 + j.
__global__ void flgc_pack(const float* __restrict__ conv, const int* __restrict__ meta,
                          unsigned short* __restrict__ wpack) {
    const float* si = (const float*)meta + M_SI;
    const float* so = (const float*)meta + M_SO;
    const int total = meta[M_WOFFE + 8];
    for (int idx = blockIdx.x * blockDim.x + threadIdx.x; idx < total;
         idx += gridDim.x * blockDim.x) {
        int gg = 0;
        while (gg < 7 && idx >= meta[M_WOFFE + gg + 1]) ++gg;
        const int local = idx - meta[M_WOFFE + gg];
        const int fcnt = meta[M_FCNT + gg], ccnt = meta[M_CCNT + gg];
        const int mfall = (fcnt + 15) >> 4;
        const int fragidx = local >> 9, e = local & 511;
        const int lane = e >> 3, j = e & 7;
        const int tap = fragidx % 9, t2 = fragidx / 9;
        const int mf = t2 % mfall, q = t2 / mfall;
        const int fl = mf * 16 + (lane & 15);
        const int cl = q * 32 + (lane >> 4) * 8 + j;
        float v = 0.f;
        if (fl < fcnt && cl < ccnt) {
            const int F  = meta[M_FLIST + meta[M_FBASE + gg] + fl];
            const int CH = meta[M_CLIST + meta[M_CBASE + gg] + cl];
            v = conv[(F * 256 + CH) * 9 + tap] * si[CH] * so[F];
        }
        wpack[idx] = f2bf(v);
    }
}

// ---- reorder x -> xr[g*2+q][b][row 0..57][col 0..57][cl 0..31] bf16, zero halo.
// ILP version: 8 independent register loads per thread (no dependent chain),
// then LDS transpose, then contiguous ushort4 writes.
__global__ __launch_bounds__(256) void flgc_reorder(const float* __restrict__ x,
                                                    const int* __restrict__ meta,
                                                    unsigned short* __restrict__ xr) {
    __shared__ float lds[32][65];
    const int r = blockIdx.x;           // xr row 0..57
    const int b = blockIdx.y;
    const int slot = blockIdx.z;        // g*2+q
    const int g = slot >> 1, q = slot & 1;
    const int ccnt = meta[M_CCNT + g];
    int nq = (ccnt + 31) >> 5; if (nq > 2) nq = 2;
    if (q >= nq) return;
    const int cbas = meta[M_CBASE + g];
    const int row = r - 1;
    const int colx = threadIdx.x & 63;
    const int cl0 = threadIdx.x >> 6;   // 0..3 (wave id)
    const int ic = colx - 1;
    const bool ok = ((unsigned)row < 56u) && ((unsigned)ic < 56u);

    int chn[8];
#pragma unroll
    for (int i = 0; i < 8; ++i) {
        const int cgl = q * 32 + cl0 + i * 4;
        chn[i] = (cgl < ccnt) ? meta[M_CLIST + cbas + cgl] : -1;
    }
    const float* xb = x + (size_t)b * 256 * 3136 + row * 56 + ic;
    float v[8];
#pragma unroll
    for (int i = 0; i < 8; ++i) v[i] = 0.f;
#pragma unroll
    for (int i = 0; i < 8; ++i)          // 8 independent loads, all in flight
        if (ok && chn[i] >= 0) v[i] = xb[(size_t)chn[i] * 3136];
#pragma unroll
    for (int i = 0; i < 8; ++i) lds[cl0 + i * 4][colx] = v[i];
    __syncthreads();

    unsigned short* dst = xr + (size_t)(slot * 32 + b) * 107648ull + r * 58 * 32;
    // i -> addr i*8 bytes: perfectly contiguous block-wide ushort4 stores
    for (int i = threadIdx.x; i < 58 * 8; i += 256) {
        const int col = i >> 3, cl4 = (i & 7) * 4;
        ushort4 pk = make_ushort4(f2bf(lds[cl4 + 0][col]), f2bf(lds[cl4 + 1][col]),
                                  f2bf(lds[cl4 + 2][col]), f2bf(lds[cl4 + 3][col]));
        *(ushort4*)&dst[col * 32 + cl4] = pk;
    }
}

// ---- conv: block=(stripe,b,g); 4 waves; tile staged via global_load_lds.
// LDS x tile: [row 0..9][col 0..57][cl 0..31] bf16 = 37120 B (alloc 37888 incl. slack).
__global__ __launch_bounds__(256, 2) void flgc_conv_f(const int* __restrict__ meta,
                                                      const unsigned short* __restrict__ wpack,
                                                      const unsigned short* __restrict__ xr,
                                                      float* __restrict__ out) {
    __shared__ __align__(16) unsigned short xbuf[18944];   // 37888 B
    __shared__ __align__(16) unsigned short wbuf[13824];   // 27648 B (3 mf x 9 taps x 512)
    const int g = blockIdx.z, b = blockIdx.y, h0 = blockIdx.x * 8;
    const int tid = threadIdx.x, lane = tid & 63, wv = tid >> 6;
    const int ccnt = meta[M_CCNT + g], fcnt = meta[M_FCNT + g];
    const int fbas = meta[M_FBASE + g];
    const int woffe = meta[M_WOFFE + g];
    int nq = (ccnt + 31) >> 5; if (nq > 2) nq = 2;
    const int mfall = (fcnt + 15) >> 4;
    if (mfall == 0) return;
    const int n = lane & 15, kg = lane >> 4;
    const int prow = 2 * wv + (n >> 3), pcol = n & 7;

    for (int mf0 = 0; mf0 < mfall; mf0 += 3) {
        const int mfe = min(3, mfall - mf0);
        f32x4 acc[3][7];
#pragma unroll
        for (int mf = 0; mf < 3; ++mf)
#pragma unroll
            for (int cg = 0; cg < 7; ++cg) acc[mf][cg] = (f32x4){0.f, 0.f, 0.f, 0.f};

        for (int q = 0; q < nq; ++q) {
            __syncthreads();
            // x tile: 37 x 1KB wave-calls (768B tail slack covered by xr over-alloc)
            const char* tbase = (const char*)(xr + (size_t)((g * 2 + q) * 32 + b) * 107648ull
                                              + (size_t)h0 * 58 * 32);
            for (int k = wv; k < 37; k += 4)
                gl_lds16(tbase + k * 1024 + lane * 16, (char*)xbuf + k * 1024);
            // weight fragments for this (q, mf-block): mfe*9 x 1KB wave-calls
            const char* wsrc = (const char*)(wpack + woffe + (size_t)(q * mfall + mf0) * 9 * 512);
            for (int k = wv; k < mfe * 9; k += 4)
                gl_lds16(wsrc + k * 1024 + lane * 16, (char*)wbuf + k * 1024);
            __syncthreads();   // drains vmcnt(0) before barrier (compiler-enforced)
#pragma unroll
            for (int tap = 0; tap < 9; ++tap) {
                const int dr = tap / 3, dc = tap - dr * 3;
                bf16x8 A[3];
#pragma unroll
                for (int mf = 0; mf < 3; ++mf)
                    if (mf < mfe)
                        A[mf] = *(bf16x8*)&wbuf[(mf * 9 + tap) * 512 + lane * 8];
                const int rb = (prow + dr) * 58;
#pragma unroll
                for (int cg = 0; cg < 7; ++cg) {
                    const int colx = pcol + cg * 8 + dc;
                    const bf16x8 B = *(bf16x8*)&xbuf[(rb + colx) * 32 + kg * 8];
#pragma unroll
                    for (int mf = 0; mf < 3; ++mf)
                        if (mf < mfe)
                            acc[mf][cg] = __builtin_amdgcn_mfma_f32_16x16x32_bf16(
                                A[mf], B, acc[mf][cg], 0, 0, 0);
                }
            }
        }
        // epilogue: C frag col = lane&15 (pixel), row = (lane>>4)*4 + reg (filter)
#pragma unroll
        for (int mf = 0; mf < 3; ++mf) {
            if (mf < mfe) {
#pragma unroll
                for (int reg = 0; reg < 4; ++reg) {
                    const int fl = (mf0 + mf) * 16 + (lane >> 4) * 4 + reg;
                    if (fl < fcnt) {
                        const int F  = meta[M_FLIST + fbas + fl];
                        const int oc = meta[M_DEST + F];
                        float* op = out + ((size_t)(b * 256 + oc) * 56 + (h0 + prow)) * 56 + pcol;
#pragma unroll
                        for (int cg = 0; cg < 7; ++cg)
                            op[cg * 8] = acc[mf][cg][reg];
                    }
                }
            }
        }
    }
}

// ---- fallback (small ws): round-2 direct-gather MFMA kernel, known-good.
__global__ __launch_bounds__(256, 2) void flgc_conv_mfma(const float* __restrict__ x,
                                                         const int* __restrict__ meta,
                                                         const unsigned short* __restrict__ wpack,
                                                         float* __restrict__ out) {
    __shared__ __align__(16) unsigned short xlds[10 * 4 * 64 * 8];
    __shared__ __align__(16) unsigned short wlds[4 * 9 * 512];
    const int g = blockIdx.z, b = blockIdx.y, h0 = blockIdx.x * 8;
    const int tid = threadIdx.x, lane = tid & 63, wv = tid >> 6;
    const int ccnt = meta[M_CCNT + g], fcnt = meta[M_FCNT + g];
    const int cbas = meta[M_CBASE + g], fbas = meta[M_FBASE + g];
    const int woffe = meta[M_WOFFE + g];
    const int nq = (ccnt + 31) >> 5, mfall = (fcnt + 15) >> 4;
    if (mfall == 0) return;
    const int n = lane & 15, kgl = lane >> 4;
    const int prow = 2 * wv + (n >> 3);
    const int pcol = n & 7;

    for (int mf0 = 0; mf0 < mfall; mf0 += 4) {
        const int mfe = min(4, mfall - mf0);
        f32x4 acc[4][7];
#pragma unroll
        for (int mf = 0; mf < 4; ++mf)
#pragma unroll
            for (int cg = 0; cg < 7; ++cg) acc[mf][cg] = (f32x4){0.f, 0.f, 0.f, 0.f};

        for (int q = 0; q < nq; ++q) {
            __syncthreads();
            for (int widx = wv; widx < mfe * 9; widx += 4) {
                const int mf = widx / 9, tap = widx - mf * 9;
                const unsigned short* src =
                    wpack + woffe + (((q * mfall) + mf0 + mf) * 9 + tap) * 512 + lane * 8;
                *(bf16x8*)&wlds[(mf * 9 + tap) * 512 + lane * 8] = *(const bf16x8*)src;
            }
            for (int i = tid; i < 80 * 64; i += 256) {
                const int colx = i & 63, t = i >> 6;
                const int rr = t >> 3, cq = t & 7;
                const int c0 = q * 32 + cq * 4;
                const int row = h0 + rr - 1, ic = colx - 1;
                float v0 = 0.f, v1 = 0.f, v2 = 0.f, v3 = 0.f;
                if ((unsigned)row < 56u && (unsigned)ic < 56u) {
                    const float* xp = x + (size_t)(b * 256) * 3136 + row * 56 + ic;
                    if (c0 + 0 < ccnt) v0 = xp[(size_t)meta[M_CLIST + cbas + c0 + 0] * 3136];
                    if (c0 + 1 < ccnt) v1 = xp[(size_t)meta[M_CLIST + cbas + c0 + 1] * 3136];
                    if (c0 + 2 < ccnt) v2 = xp[(size_t)meta[M_CLIST + cbas + c0 + 2] * 3136];
                    if (c0 + 3 < ccnt) v3 = xp[(size_t)meta[M_CLIST + cbas + c0 + 3] * 3136];
                }
                ushort4 pk = make_ushort4(f2bf(v0), f2bf(v1), f2bf(v2), f2bf(v3));
                *(ushort4*)&xlds[(((rr * 4 + (cq >> 1)) * 64 + colx) << 3) + ((cq & 1) << 2)] = pk;
            }
            __syncthreads();
#pragma unroll
            for (int tap = 0; tap < 9; ++tap) {
                const int dr = tap / 3, dcp = tap - dr * 3;
                bf16x8 A[4];
#pragma unroll
                for (int mf = 0; mf < 4; ++mf)
                    if (mf < mfe)
                        A[mf] = *(bf16x8*)&wlds[(mf * 9 + tap) * 512 + lane * 8];
                const int row_r = prow + dr;
                const int xbase = ((row_r * 4 + kgl) * 64) << 3;
#pragma unroll
                for (int cg = 0; cg < 7; ++cg) {
                    const int cc = cg * 8 + pcol + dcp;
                    const bf16x8 B = *(bf16x8*)&xlds[xbase + (cc << 3)];
#pragma unroll
                    for (int mf = 0; mf < 4; ++mf)
                        if (mf < mfe)
                            acc[mf][cg] = __builtin_amdgcn_mfma_f32_16x16x32_bf16(
                                A[mf], B, acc[mf][cg], 0, 0, 0);
                }
            }
        }
#pragma unroll
        for (int mf = 0; mf < 4; ++mf) {
            if (mf < mfe) {
#pragma unroll
                for (int reg = 0; reg < 4; ++reg) {
                    const int fl = (mf0 + mf) * 16 + (lane >> 4) * 4 + reg;
                    if (fl < fcnt) {
                        const int F  = meta[M_FLIST + fbas + fl];
                        const int oc = meta[M_DEST + F];
                        float* op = out + ((size_t)(b * 256 + oc) * 56 + (h0 + prow)) * 56 + pcol;
#pragma unroll
                        for (int cg = 0; cg < 7; ++cg)
                            op[cg * 8] = acc[mf][cg][reg];
                    }
                }
            }
        }
    }
}

extern "C" void kernel_launch(void* const* d_in, const int* in_sizes, int n_in,
                              void* d_out, int out_size, void* d_ws, size_t ws_size,
                              hipStream_t stream) {
    const float* x    = (const float*)d_in[0];   // [32,256,56,56]
    const float* conv = (const float*)d_in[1];   // [256,256,3,3]
    const float* S    = (const float*)d_in[2];   // [256,8]
    const float* T    = (const float*)d_in[3];   // [256,8]
    float* out = (float*)d_out;                  // [32,256,56,56]
    int* meta = (int*)d_ws;
    unsigned short* wpack = (unsigned short*)((char*)d_ws + WPACK_BYTE_OFF);
    unsigned short* xr    = (unsigned short*)((char*)d_ws + XR_BYTE_OFF);

    flgc_setup<<<1, 256, 0, stream>>>(S, T, meta);
    flgc_pack<<<256, 256, 0, stream>>>(conv, meta, wpack);

    const size_t need = (size_t)XR_BYTE_OFF + 16ull * SLOT_BYTES + 4096;
    if (ws_size >= need) {
        flgc_reorder<<<dim3(58, 32, 16), 256, 0, stream>>>(x, meta, xr);
        flgc_conv_f<<<dim3(7, 32, 8), 256, 0, stream>>>(meta, wpack, xr, out);
    } else {
        flgc_conv_mfma<<<dim3(7, 32, 8), 256, 0, stream>>>(x, meta, wpack, out);
    }
}